// Round 1
// baseline (2529.506 us; speedup 1.0000x reference)
//
#include <hip/hip_runtime.h>

// Problem constants
#define B_SZ  4
#define T_LEN 2048
#define C_DIM 768
#define H_NUM 12
#define D_DIM 64

// ---------------------------------------------------------------------------
// SGEMM: Cout[M,N] = A[M,K] @ B[K,N] + bias[N]
// BM=BN=128, BK=8, 256 threads, 8x8 microtile per thread.
// All dims divide evenly for our shapes (M=8192, N in {2304,768}, K=768).
// ---------------------------------------------------------------------------
__global__ __launch_bounds__(256) void sgemm_bias_kernel(
    const float* __restrict__ A, const float* __restrict__ B,
    const float* __restrict__ bias, float* __restrict__ Cout,
    int M, int N, int K) {
  __shared__ float As[128][9];   // [m][k], pad to 9 to break write conflicts
  __shared__ float Bs[8][128];   // [k][n]

  const int tid = threadIdx.x;
  const int ty = tid >> 4;   // 0..15 -> row group
  const int tx = tid & 15;   // 0..15 -> col group
  const int row0 = blockIdx.y * 128;
  const int col0 = blockIdx.x * 128;

  float acc[8][8];
#pragma unroll
  for (int r = 0; r < 8; ++r)
#pragma unroll
    for (int c = 0; c < 8; ++c) acc[r][c] = 0.f;

  for (int k0 = 0; k0 < K; k0 += 8) {
    // Load A tile: 128x8 (1024 floats, 4/thread)
#pragma unroll
    for (int i = 0; i < 4; ++i) {
      int idx = tid + i * 256;
      int m = idx >> 3, kk = idx & 7;
      As[m][kk] = A[(size_t)(row0 + m) * K + (k0 + kk)];
    }
    // Load B tile: 8x128 (1024 floats, 4/thread, coalesced)
#pragma unroll
    for (int i = 0; i < 4; ++i) {
      int idx = tid + i * 256;
      int kk = idx >> 7, n = idx & 127;
      Bs[kk][n] = B[(size_t)(k0 + kk) * N + (col0 + n)];
    }
    __syncthreads();
#pragma unroll
    for (int k = 0; k < 8; ++k) {
      float a[8], b[8];
#pragma unroll
      for (int r = 0; r < 8; ++r) a[r] = As[ty * 8 + r][k];
#pragma unroll
      for (int c = 0; c < 8; ++c) b[c] = Bs[k][tx * 8 + c];
#pragma unroll
      for (int r = 0; r < 8; ++r)
#pragma unroll
        for (int c = 0; c < 8; ++c) acc[r][c] += a[r] * b[c];
    }
    __syncthreads();
  }

#pragma unroll
  for (int r = 0; r < 8; ++r) {
    const size_t gr = (size_t)(row0 + ty * 8 + r);
#pragma unroll
    for (int c = 0; c < 8; ++c) {
      const int gc = col0 + tx * 8 + c;
      Cout[gr * N + gc] = acc[r][c] + bias[gc];
    }
  }
}

// ---------------------------------------------------------------------------
// Causal flash attention, fp32.
// qkv: [B*T, 3C] with Q at col h*64, K at col C + h*64, V at col 2C + h*64.
// y:   [B*T, C]  (head-contiguous -> directly feeds proj GEMM).
// Grid: (B*H, T/256). Block: 256 threads, one query row per thread.
// K/V staged in LDS 64 rows at a time; broadcast LDS reads (uniform address
// across the wave -> conflict-free). Online softmax in chunks of 16 keys.
// Causal tile-skip is wave-uniform (wave = 64 consecutive rows, tiles = 64).
// ---------------------------------------------------------------------------
__global__ __launch_bounds__(256) void flash_attn_kernel(
    const float* __restrict__ qkv, float* __restrict__ y) {
  __shared__ __align__(16) float Kt[64][64];
  __shared__ __align__(16) float Vt[64][64];

  const int bh = blockIdx.x;          // 0..47
  const int qt = blockIdx.y;          // 0..7
  const int b = bh / H_NUM;
  const int h = bh % H_NUM;
  const int t = threadIdx.x;          // 0..255
  const int q_row = qt * 256 + t;

  const int threeC = 3 * C_DIM;
  const size_t qbase = (size_t)(b * T_LEN + q_row) * threeC + h * 64;

  float q[64];
#pragma unroll
  for (int d4 = 0; d4 < 16; ++d4) {
    float4 v = *(const float4*)&qkv[qbase + d4 * 4];
    q[d4 * 4 + 0] = v.x * 0.125f;   // 1/sqrt(64)
    q[d4 * 4 + 1] = v.y * 0.125f;
    q[d4 * 4 + 2] = v.z * 0.125f;
    q[d4 * 4 + 3] = v.w * 0.125f;
  }

  float o[64];
#pragma unroll
  for (int d = 0; d < 64; ++d) o[d] = 0.f;
  float m = -1e30f, l = 0.f;

  const int n_tiles = qt * 4 + 4;     // keys 0 .. qt*256+255
  for (int kt = 0; kt < n_tiles; ++kt) {
    const int j0 = kt * 64;
    __syncthreads();
    // Stage K,V tiles: 64 rows x 64 cols each; float4 loads, 4/thread each.
#pragma unroll
    for (int i = 0; i < 4; ++i) {
      int idx = t + i * 256;          // float4 index, 0..1023
      int r = idx >> 4, c4 = idx & 15;
      size_t base = (size_t)(b * T_LEN + j0 + r) * threeC + h * 64 + c4 * 4;
      *(float4*)&Kt[r][c4 * 4] = *(const float4*)&qkv[base + C_DIM];
      *(float4*)&Vt[r][c4 * 4] = *(const float4*)&qkv[base + 2 * C_DIM];
    }
    __syncthreads();

    if (q_row >= j0) {                // wave-uniform skip for masked tiles
#pragma unroll 1
      for (int jc = 0; jc < 64; jc += 16) {
        float s[16];
        float cmax = -1e30f;
#pragma unroll
        for (int jj = 0; jj < 16; ++jj) {
          float dot = 0.f;
#pragma unroll
          for (int d4 = 0; d4 < 16; ++d4) {
            float4 kv = *(const float4*)&Kt[jc + jj][d4 * 4];
            dot += q[d4 * 4 + 0] * kv.x + q[d4 * 4 + 1] * kv.y +
                   q[d4 * 4 + 2] * kv.z + q[d4 * 4 + 3] * kv.w;
          }
          dot = (j0 + jc + jj <= q_row) ? dot : -1e30f;
          s[jj] = dot;
          cmax = fmaxf(cmax, dot);
        }
        const float m_new = fmaxf(m, cmax);
        const float alpha = __expf(m - m_new);
        float psum = 0.f;
#pragma unroll
        for (int jj = 0; jj < 16; ++jj) {
          s[jj] = __expf(s[jj] - m_new);
          psum += s[jj];
        }
        l = l * alpha + psum;
        m = m_new;
#pragma unroll
        for (int d = 0; d < 64; ++d) o[d] *= alpha;
#pragma unroll
        for (int jj = 0; jj < 16; ++jj) {
          const float p = s[jj];
#pragma unroll
          for (int d4 = 0; d4 < 16; ++d4) {
            float4 vv = *(const float4*)&Vt[jc + jj][d4 * 4];
            o[d4 * 4 + 0] += p * vv.x;
            o[d4 * 4 + 1] += p * vv.y;
            o[d4 * 4 + 2] += p * vv.z;
            o[d4 * 4 + 3] += p * vv.w;
          }
        }
      }
    }
  }

  const float inv_l = 1.f / l;
  const size_t orow = (size_t)(b * T_LEN + q_row) * C_DIM + h * 64;
#pragma unroll
  for (int d4 = 0; d4 < 16; ++d4) {
    float4 v;
    v.x = o[d4 * 4 + 0] * inv_l;
    v.y = o[d4 * 4 + 1] * inv_l;
    v.z = o[d4 * 4 + 2] * inv_l;
    v.w = o[d4 * 4 + 3] * inv_l;
    *(float4*)&y[orow + d4 * 4] = v;
  }
}

// ---------------------------------------------------------------------------
extern "C" void kernel_launch(void* const* d_in, const int* in_sizes, int n_in,
                              void* d_out, int out_size, void* d_ws, size_t ws_size,
                              hipStream_t stream) {
  const float* x      = (const float*)d_in[0];  // [B,T,C]
  const float* W_attn = (const float*)d_in[1];  // [C,3C]
  const float* b_attn = (const float*)d_in[2];  // [3C]
  const float* W_proj = (const float*)d_in[3];  // [C,C]
  const float* b_proj = (const float*)d_in[4];  // [C]
  float* out = (float*)d_out;                   // [B,T,C]

  const int M = B_SZ * T_LEN;                   // 8192
  float* qkv = (float*)d_ws;                                        // [M,3C] = 75.5 MB
  float* y   = (float*)((char*)d_ws + (size_t)M * 3 * C_DIM * 4);   // [M,C]  = 25.2 MB

  // 1) qkv = x @ W_attn + b_attn
  dim3 g1(3 * C_DIM / 128, M / 128);  // (18, 64)
  sgemm_bias_kernel<<<g1, 256, 0, stream>>>(x, W_attn, b_attn, qkv, M, 3 * C_DIM, C_DIM);

  // 2) y = causal_attention(qkv)
  dim3 g2(B_SZ * H_NUM, T_LEN / 256); // (48, 8)
  flash_attn_kernel<<<g2, 256, 0, stream>>>(qkv, y);

  // 3) out = y @ W_proj + b_proj
  dim3 g3(C_DIM / 128, M / 128);      // (6, 64)
  sgemm_bias_kernel<<<g3, 256, 0, stream>>>(y, W_proj, b_proj, out, M, C_DIM, C_DIM);
}

// Round 2
// 257.963 us; speedup vs baseline: 9.8057x; 9.8057x over previous
//
#include <hip/hip_runtime.h>

#define B_SZ   4
#define T_LEN  2048
#define C_DIM  768
#define H_NUM  12
#define D_DIM  64
#define THREEC (3 * C_DIM)

typedef _Float16 f16;
typedef _Float16 half8 __attribute__((ext_vector_type(8)));
typedef float    f32x4 __attribute__((ext_vector_type(4)));

// ---------------------------------------------------------------------------
// cast fp32 -> fp16, 8 elems/thread
// ---------------------------------------------------------------------------
__global__ __launch_bounds__(256) void cast_f32_f16_kernel(
    const float* __restrict__ src, f16* __restrict__ dst, int n8) {
  int i = blockIdx.x * 256 + threadIdx.x;
  if (i >= n8) return;
  const float* s = src + (size_t)i * 8;
  half8 h;
#pragma unroll
  for (int u = 0; u < 8; ++u) h[u] = (f16)s[u];
  *(half8*)(dst + (size_t)i * 8) = h;
}

// ---------------------------------------------------------------------------
// W[K][N] fp32 -> Wt[N][K] fp16 (32x32 LDS tile transpose)
// ---------------------------------------------------------------------------
__global__ __launch_bounds__(256) void transpose_cast_kernel(
    const float* __restrict__ W, f16* __restrict__ Wt, int K, int N) {
  __shared__ f16 tile[32][33];
  const int n0 = blockIdx.x * 32, k0 = blockIdx.y * 32;
  const int tx = threadIdx.x & 31, ty = threadIdx.x >> 5;  // ty 0..7
#pragma unroll
  for (int i = 0; i < 4; ++i) {
    int k = k0 + ty + i * 8;
    tile[ty + i * 8][tx] = (f16)W[(size_t)k * N + n0 + tx];
  }
  __syncthreads();
#pragma unroll
  for (int i = 0; i < 4; ++i) {
    int n = n0 + ty + i * 8;
    Wt[(size_t)n * K + k0 + tx] = tile[tx][ty + i * 8];
  }
}

// ---------------------------------------------------------------------------
// MFMA GEMM: C[M][N] = A[M][K] @ Bt[N][K]^T + bias, f16 in, f16/f32 out.
// 128x128 tile, BK=32, 256 threads = 4 waves, each wave 64x64 (4x4 MFMA tiles).
// mfma_f32_16x16x32_f16:
//   A-frag: m = lane&15, k = (lane>>4)*8 + j
//   B-frag: n = lane&15, k = (lane>>4)*8 + j
//   C/D:    col = lane&15, row = (lane>>4)*4 + r
// ---------------------------------------------------------------------------
template <bool OUT_F16>
__global__ __launch_bounds__(256) void gemm_f16_kernel(
    const f16* __restrict__ A, const f16* __restrict__ Bt,
    const float* __restrict__ bias, void* __restrict__ Cout,
    int M, int N, int K) {
  __shared__ f16 As[128 * 32];
  __shared__ f16 Bs[128 * 32];
  const int tid = threadIdx.x;
  const int lane = tid & 63, wave = tid >> 6;
  const int lm = lane & 15, kq = lane >> 4;
  const int wm = (wave & 1) * 64, wn = (wave >> 1) * 64;
  const int row0 = blockIdx.y * 128, col0 = blockIdx.x * 128;

  f32x4 acc[4][4] = {};

  for (int k0 = 0; k0 < K; k0 += 32) {
#pragma unroll
    for (int i = 0; i < 2; ++i) {
      int c = tid + i * 256;               // 0..511
      int mm = c >> 2, ko = (c & 3) * 8;   // row, k-offset
      *(half8*)&As[mm * 32 + ko] = *(const half8*)&A[(size_t)(row0 + mm) * K + k0 + ko];
      *(half8*)&Bs[mm * 32 + ko] = *(const half8*)&Bt[(size_t)(col0 + mm) * K + k0 + ko];
    }
    __syncthreads();
    half8 af[4], bf[4];
#pragma unroll
    for (int t = 0; t < 4; ++t) {
      af[t] = *(const half8*)&As[(wm + t * 16 + lm) * 32 + kq * 8];
      bf[t] = *(const half8*)&Bs[(wn + t * 16 + lm) * 32 + kq * 8];
    }
#pragma unroll
    for (int mt = 0; mt < 4; ++mt)
#pragma unroll
      for (int nt = 0; nt < 4; ++nt)
        acc[mt][nt] = __builtin_amdgcn_mfma_f32_16x16x32_f16(af[mt], bf[nt], acc[mt][nt], 0, 0, 0);
    __syncthreads();
  }

#pragma unroll
  for (int mt = 0; mt < 4; ++mt) {
    const int row = row0 + wm + mt * 16 + kq * 4;
#pragma unroll
    for (int nt = 0; nt < 4; ++nt) {
      const int col = col0 + wn + nt * 16 + lm;
      const float bv = bias[col];
#pragma unroll
      for (int r = 0; r < 4; ++r) {
        float v = acc[mt][nt][r] + bv;
        if (OUT_F16)
          ((f16*)Cout)[(size_t)(row + r) * N + col] = (f16)v;
        else
          ((float*)Cout)[(size_t)(row + r) * N + col] = v;
      }
    }
  }
}

// ---------------------------------------------------------------------------
// V pre-transpose: qkv[B*T][3C] (V slice) -> vt[bh][d=64][T] f16
// ---------------------------------------------------------------------------
__global__ __launch_bounds__(256) void v_transpose_kernel(
    const f16* __restrict__ qkv, f16* __restrict__ vt) {
  __shared__ f16 tile[64 * 68];
  const int bh = blockIdx.x, b = bh / H_NUM, h = bh % H_NUM;
  const int t0 = blockIdx.y * 64;
  const int tid = threadIdx.x;
#pragma unroll
  for (int i = 0; i < 2; ++i) {
    int c = tid + i * 256;
    int tr = c >> 3, doff = (c & 7) * 8;
    half8 v = *(const half8*)&qkv[(size_t)(b * T_LEN + t0 + tr) * THREEC + 2 * C_DIM + h * 64 + doff];
#pragma unroll
    for (int u = 0; u < 8; ++u) tile[(doff + u) * 68 + tr] = v[u];
  }
  __syncthreads();
#pragma unroll
  for (int i = 0; i < 2; ++i) {
    int c = tid + i * 256;
    int d = c >> 3, toff = (c & 7) * 8;
    half8 v;
#pragma unroll
    for (int u = 0; u < 8; ++u) v[u] = tile[d * 68 + toff + u];
    *(half8*)&vt[((size_t)bh * 64 + d) * T_LEN + t0 + toff] = v;
  }
}

// ---------------------------------------------------------------------------
// MFMA causal flash attention.
// Grid (B*H, T/64); block = 256 threads = 4 waves; wave w owns q rows
// q0+16w .. q0+16w+15.  K-tile & V^T-tile (64 keys) staged in LDS, stride 72
// (pad breaks 128B-row bank conflicts, keeps 16B alignment).
// ---------------------------------------------------------------------------
__global__ __launch_bounds__(256) void attn_kernel(
    const f16* __restrict__ qkv, const f16* __restrict__ vt,
    f16* __restrict__ y) {
  __shared__ f16 Kt[64 * 72];        // [key][d]
  __shared__ f16 Vt[64 * 72];        // [d? no: [d-major] -> [row=d][key]
  __shared__ f16 Pl[4][16 * 72];     // per-wave P buffer [row][key]

  const int bh = blockIdx.x, b = bh / H_NUM, h = bh % H_NUM;
  const int q0 = ((int)gridDim.y - 1 - (int)blockIdx.y) * 64;  // heavy blocks first
  const int tid = threadIdx.x;
  const int lane = tid & 63, wave = tid >> 6;
  const int lm = lane & 15, kq = lane >> 4;
  const int qw = q0 + wave * 16;

  // Q A-frags, pre-scaled by 1/sqrt(64) (exact pow2 in f16)
  half8 aq[2];
#pragma unroll
  for (int c = 0; c < 2; ++c) {
    aq[c] = *(const half8*)&qkv[(size_t)(b * T_LEN + qw + lm) * THREEC + h * 64 + c * 32 + kq * 8];
    aq[c] = aq[c] * (f16)0.125f;
  }

  f32x4 o[4] = {};
  float mrow[4], lrow[4];
#pragma unroll
  for (int r = 0; r < 4; ++r) { mrow[r] = -1e30f; lrow[r] = 0.f; }

  const int n_tiles = q0 / 64 + 1;
  for (int it = 0; it < n_tiles; ++it) {
    const int j0 = it * 64;
    // cooperative stage: Kt[key][d] from qkv, Vt[d][key] from vt
#pragma unroll
    for (int i = 0; i < 2; ++i) {
      int c = tid + i * 256;
      int r8 = c >> 3, off = (c & 7) * 8;
      *(half8*)&Kt[r8 * 72 + off] =
          *(const half8*)&qkv[(size_t)(b * T_LEN + j0 + r8) * THREEC + C_DIM + h * 64 + off];
      *(half8*)&Vt[r8 * 72 + off] =
          *(const half8*)&vt[((size_t)bh * 64 + r8) * T_LEN + j0 + off];
    }
    __syncthreads();

    if (j0 <= qw + 15) {   // wave has at least one unmasked (row,key) pair
      // S = Q @ K^T : 4 col-tiles x 2 k-chunks
      f32x4 s[4];
#pragma unroll
      for (int ct = 0; ct < 4; ++ct) {
        half8 bk0 = *(const half8*)&Kt[(ct * 16 + lm) * 72 + 0 * 32 + kq * 8];
        half8 bk1 = *(const half8*)&Kt[(ct * 16 + lm) * 72 + 1 * 32 + kq * 8];
        f32x4 z = {};
        z = __builtin_amdgcn_mfma_f32_16x16x32_f16(aq[0], bk0, z, 0, 0, 0);
        s[ct] = __builtin_amdgcn_mfma_f32_16x16x32_f16(aq[1], bk1, z, 0, 0, 0);
      }
      // causal mask + per-row max (rows live across 16-lane groups)
      float p[4][4], tmax[4];
#pragma unroll
      for (int r = 0; r < 4; ++r) tmax[r] = -1e30f;
#pragma unroll
      for (int ct = 0; ct < 4; ++ct) {
        const int jcol = j0 + ct * 16 + lm;
#pragma unroll
        for (int r = 0; r < 4; ++r) {
          const int qrow = qw + kq * 4 + r;
          float v = (jcol <= qrow) ? s[ct][r] : -1e30f;
          p[ct][r] = v;
          tmax[r] = fmaxf(tmax[r], v);
        }
      }
#pragma unroll
      for (int msk = 1; msk < 16; msk <<= 1)
#pragma unroll
        for (int r = 0; r < 4; ++r)
          tmax[r] = fmaxf(tmax[r], __shfl_xor(tmax[r], msk, 64));

      float alpha[4], rsum[4];
#pragma unroll
      for (int r = 0; r < 4; ++r) {
        const float mnew = fmaxf(mrow[r], tmax[r]);
        alpha[r] = __expf(mrow[r] - mnew);
        mrow[r] = mnew;
        rsum[r] = 0.f;
      }
#pragma unroll
      for (int ct = 0; ct < 4; ++ct)
#pragma unroll
        for (int r = 0; r < 4; ++r) {
          const float e = __expf(p[ct][r] - mrow[r]);
          p[ct][r] = e;
          rsum[r] += e;
        }
#pragma unroll
      for (int msk = 1; msk < 16; msk <<= 1)
#pragma unroll
        for (int r = 0; r < 4; ++r)
          rsum[r] += __shfl_xor(rsum[r], msk, 64);
#pragma unroll
      for (int r = 0; r < 4; ++r) lrow[r] = lrow[r] * alpha[r] + rsum[r];
      // rescale O (same row layout as S)
#pragma unroll
      for (int nt = 0; nt < 4; ++nt)
#pragma unroll
        for (int r = 0; r < 4; ++r) o[nt][r] *= alpha[r];
      // P: C-layout -> row-major LDS [row][key] (per-wave buffer)
      f16* pw = &Pl[wave][0];
#pragma unroll
      for (int ct = 0; ct < 4; ++ct)
#pragma unroll
        for (int r = 0; r < 4; ++r)
          pw[(kq * 4 + r) * 72 + ct * 16 + lm] = (f16)p[ct][r];
      __asm__ volatile("s_waitcnt lgkmcnt(0)" ::: "memory");
      // PV: O += P @ V   (A = P row-major, B = Vt rows = d)
      half8 ap0 = *(const half8*)&pw[lm * 72 + 0 * 32 + kq * 8];
      half8 ap1 = *(const half8*)&pw[lm * 72 + 1 * 32 + kq * 8];
#pragma unroll
      for (int nt = 0; nt < 4; ++nt) {
        half8 bv0 = *(const half8*)&Vt[(nt * 16 + lm) * 72 + 0 * 32 + kq * 8];
        half8 bv1 = *(const half8*)&Vt[(nt * 16 + lm) * 72 + 1 * 32 + kq * 8];
        o[nt] = __builtin_amdgcn_mfma_f32_16x16x32_f16(ap0, bv0, o[nt], 0, 0, 0);
        o[nt] = __builtin_amdgcn_mfma_f32_16x16x32_f16(ap1, bv1, o[nt], 0, 0, 0);
      }
    }
    __syncthreads();
  }

#pragma unroll
  for (int r = 0; r < 4; ++r) {
    const float inv = 1.f / lrow[r];
    const int qrow = qw + kq * 4 + r;
    const size_t base = (size_t)(b * T_LEN + qrow) * C_DIM + h * 64;
#pragma unroll
    for (int nt = 0; nt < 4; ++nt)
      y[base + nt * 16 + lm] = (f16)(o[nt][r] * inv);
  }
}

// ---------------------------------------------------------------------------
extern "C" void kernel_launch(void* const* d_in, const int* in_sizes, int n_in,
                              void* d_out, int out_size, void* d_ws, size_t ws_size,
                              hipStream_t stream) {
  const float* x      = (const float*)d_in[0];
  const float* W_attn = (const float*)d_in[1];
  const float* b_attn = (const float*)d_in[2];
  const float* W_proj = (const float*)d_in[3];
  const float* b_proj = (const float*)d_in[4];
  float* out = (float*)d_out;

  const int M = B_SZ * T_LEN;  // 8192
  auto align256 = [](size_t v) { return (v + 255) & ~(size_t)255; };
  char* ws = (char*)d_ws;
  f16* xh  = (f16*)ws;  ws += align256((size_t)M * C_DIM * 2);
  f16* WtA = (f16*)ws;  ws += align256((size_t)THREEC * C_DIM * 2);
  f16* WtP = (f16*)ws;  ws += align256((size_t)C_DIM * C_DIM * 2);
  f16* qkvh = (f16*)ws; ws += align256((size_t)M * THREEC * 2);
  f16* vtg = (f16*)ws;  ws += align256((size_t)B_SZ * H_NUM * 64 * T_LEN * 2);
  f16* yh  = (f16*)ws;  ws += align256((size_t)M * C_DIM * 2);

  // casts / transposes
  {
    int n8 = M * C_DIM / 8;
    cast_f32_f16_kernel<<<(n8 + 255) / 256, 256, 0, stream>>>(x, xh, n8);
  }
  transpose_cast_kernel<<<dim3(THREEC / 32, C_DIM / 32), 256, 0, stream>>>(W_attn, WtA, C_DIM, THREEC);
  transpose_cast_kernel<<<dim3(C_DIM / 32, C_DIM / 32), 256, 0, stream>>>(W_proj, WtP, C_DIM, C_DIM);

  // qkv = x @ W_attn + b_attn   (f16 out)
  gemm_f16_kernel<true><<<dim3(THREEC / 128, M / 128), 256, 0, stream>>>(
      xh, WtA, b_attn, qkvh, M, THREEC, C_DIM);

  // V transpose for attention PV B-frags
  v_transpose_kernel<<<dim3(B_SZ * H_NUM, T_LEN / 64), 256, 0, stream>>>(qkvh, vtg);

  // y = causal attention
  attn_kernel<<<dim3(B_SZ * H_NUM, T_LEN / 64), 256, 0, stream>>>(qkvh, vtg, yh);

  // out = y @ W_proj + b_proj   (f32 out)
  gemm_f16_kernel<false><<<dim3(C_DIM / 128, M / 128), 256, 0, stream>>>(
      yh, WtP, b_proj, out, M, C_DIM, C_DIM);
}